// Round 2
// baseline (3858.142 us; speedup 1.0000x reference)
//
#include <hip/hip_runtime.h>
#include <cstdint>

// DecoderAttentionRotary: B=2, L=2048, D=2048, H=16, HD=128, R=32 (rotary dims)
// fp32 throughout (CDNA4 has no fp32 MFMA -> vector ALU). Correctness-first baseline.
// Workspace layout (needs 128 MB): Q | K | V | O, each B*H*L*HD = 8M floats.

namespace {

constexpr int B_ = 2, L_ = 2048, D_ = 2048, H_ = 16, HD_ = 128, R_ = 32;
constexpr float SCALE_ = 0.08838834764831845f;   // 128^-0.5

// ---------------------------------------------------------------------------
// SGEMM: C[M,N] = A[M,K] * W[K,N] + bias[N]
// MODE 0: plain row-major write to Cout
// MODE 1: scatter into Q/K/V with (B,H,L,HD) layout (bias fused)
// Tile 128x128, BK=16, 256 threads, 8x8 per thread (split 4+4 rows/cols).
// BK=16: halves barrier count vs BK=8 (barrier drain is the structural stall).
// ---------------------------------------------------------------------------
template <int MODE>
__global__ __launch_bounds__(256) void sgemm_k(
    const float* __restrict__ A, const float* __restrict__ W,
    const float* __restrict__ bias, float* __restrict__ Cout,
    float* __restrict__ Qp, float* __restrict__ Kp, float* __restrict__ Vp,
    int M, int N, int Kd)
{
    const int tid = threadIdx.x;
    const int tx = tid & 15, ty = tid >> 4;
    const int n0 = blockIdx.x * 128, m0 = blockIdx.y * 128;

    __shared__ float As[16][128];   // transposed: As[kk][m]
    __shared__ float Bs[16][128];   // natural:    Bs[kk][n]

    float acc[8][8] = {};

    // A staging: thread -> (row, 8-float k chunk = 2x float4)
    const int arow = tid >> 1, au = (tid & 1) * 8;
    // B staging: thread -> (k rows brow, brow+8; 4-float n chunk); coalesced
    const int brow = tid >> 5, bcol = (tid & 31) * 4;

    const float* Ap = A + (size_t)(m0 + arow) * Kd + au;
    const float* Wp = W + (size_t)brow * N + n0 + bcol;

    float4 av0 = *(const float4*)Ap;
    float4 av1 = *(const float4*)(Ap + 4);
    float4 bv0 = *(const float4*)Wp;
    float4 bv1 = *(const float4*)(Wp + (size_t)8 * N);

    for (int k0 = 0; k0 < Kd; k0 += 16) {
        __syncthreads();
        As[au + 0][arow] = av0.x;   // 2-way bank alias across lanes: free
        As[au + 1][arow] = av0.y;
        As[au + 2][arow] = av0.z;
        As[au + 3][arow] = av0.w;
        As[au + 4][arow] = av1.x;
        As[au + 5][arow] = av1.y;
        As[au + 6][arow] = av1.z;
        As[au + 7][arow] = av1.w;
        *(float4*)&Bs[brow][bcol]     = bv0;
        *(float4*)&Bs[brow + 8][bcol] = bv1;
        __syncthreads();
        if (k0 + 16 < Kd) {        // prefetch next K-step (hides under compute)
            av0 = *(const float4*)(Ap + k0 + 16);
            av1 = *(const float4*)(Ap + k0 + 20);
            bv0 = *(const float4*)(Wp + (size_t)(k0 + 16) * N);
            bv1 = *(const float4*)(Wp + (size_t)(k0 + 24) * N);
        }
        #pragma unroll
        for (int kk = 0; kk < 16; ++kk) {
            float a[8], b[8];
            *(float4*)&a[0] = *(const float4*)&As[kk][ty * 4];
            *(float4*)&a[4] = *(const float4*)&As[kk][64 + ty * 4];
            *(float4*)&b[0] = *(const float4*)&Bs[kk][tx * 4];
            *(float4*)&b[4] = *(const float4*)&Bs[kk][64 + tx * 4];
            #pragma unroll
            for (int i = 0; i < 8; ++i)
                #pragma unroll
                for (int j = 0; j < 8; ++j)
                    acc[i][j] = fmaf(a[i], b[j], acc[i][j]);
        }
    }

    #pragma unroll
    for (int j = 0; j < 8; ++j) {
        const int n = n0 + tx * 4 + ((j >> 2) * 64) + (j & 3);
        const float bn = bias[n];
        #pragma unroll
        for (int i = 0; i < 8; ++i) {
            const int m = m0 + ty * 4 + ((i >> 2) * 64) + (i & 3);
            const float v = acc[i][j] + bn;
            if (MODE == 0) {
                Cout[(size_t)m * N + n] = v;
            } else {
                // n in [0,6144): head h = n/384, r = n%384 -> Q/K/V + dim
                const int b = m >> 11;          // m / L_
                const int l = m & (L_ - 1);
                const int h = n / 384;
                const int r = n - h * 384;
                const size_t base = ((size_t)(b * H_ + h) * L_ + l) * HD_;
                if (r < HD_)            Qp[base + r] = v;
                else if (r < 2 * HD_)   Kp[base + r - HD_] = v;
                else                    Vp[base + r - 2 * HD_] = v;
            }
        }
    }
}

// ---------------------------------------------------------------------------
// NeoX RoPE in place on Q and K, first R_=32 dims. cos/sin: [L, R] fp32,
// cos[l][j+16] == cos[l][j]. One thread per (b,h,l,j<16) pair.
// ---------------------------------------------------------------------------
__global__ __launch_bounds__(256) void rope_k(
    float* __restrict__ Qp, float* __restrict__ Kp,
    const float* __restrict__ cosp, const float* __restrict__ sinp)
{
    const int idx = blockIdx.x * 256 + threadIdx.x;   // B*H*L*16 total
    const int j = idx & 15;
    const int bhl = idx >> 4;
    const int l = bhl & (L_ - 1);
    const float c = cosp[l * R_ + j];
    const float s = sinp[l * R_ + j];
    float* qp = Qp + (size_t)bhl * HD_;
    float* kp = Kp + (size_t)bhl * HD_;
    const float q1 = qp[j], q2 = qp[j + 16];
    qp[j]      = q1 * c - q2 * s;
    qp[j + 16] = q2 * c + q1 * s;
    const float k1 = kp[j], k2 = kp[j + 16];
    kp[j]      = k1 * c - k2 * s;
    kp[j + 16] = k2 * c + k1 * s;
}

// ---------------------------------------------------------------------------
// Flash attention (causal), fp32 vector ALU.
// Block: 256 threads, BQ=64 query rows per block, 4 lanes per row (s4=0..3).
// Q held in registers: lane owns 32 interleaved dims c(d) = (d/4)*16 + s4*4 + d%4
//   -> Ks/Vs b128 reads hit 4 distinct banks (conflict-free), O write coalesced.
// Partial dots reduced via shfl_xor(1),(2) butterfly over the aligned 4-lane
// group; all 4 lanes then hold the full 32 scores -> softmax is lane-local.
// LDS: K+V tiles only, 32 KB -> ~3 blocks/CU.
// ---------------------------------------------------------------------------
constexpr int BQ_ = 64, BKV_ = 32;

__global__ __launch_bounds__(256) void attn_k(
    const float* __restrict__ Qp, const float* __restrict__ Kp,
    const float* __restrict__ Vp, float* __restrict__ Op)
{
    const int tid = threadIdx.x;
    const int bh = blockIdx.y;                           // b*H + h
    const int qt = (int)gridDim.x - 1 - (int)blockIdx.x; // heavy tiles first
    const int q0 = qt * BQ_;
    const int qloc = tid >> 2;
    const int s4 = tid & 3;
    const int qg = q0 + qloc;

    __shared__ float Ks[BKV_][HD_];
    __shared__ float Vs[BKV_][HD_];

    const float* Qb = Qp + (size_t)bh * L_ * HD_;
    const float* Kb = Kp + (size_t)bh * L_ * HD_;
    const float* Vb = Vp + (size_t)bh * L_ * HD_;

    // Q row -> registers (interleaved dims)
    float qr[32];
    #pragma unroll
    for (int d8 = 0; d8 < 8; ++d8) {
        const float4 t = *(const float4*)&Qb[(size_t)qg * HD_ + d8 * 16 + s4 * 4];
        qr[d8 * 4 + 0] = t.x; qr[d8 * 4 + 1] = t.y;
        qr[d8 * 4 + 2] = t.z; qr[d8 * 4 + 3] = t.w;
    }

    float m_run = -1e30f, l_run = 0.f;
    float acc[32] = {};

    const int srow = tid >> 5, sc4 = (tid & 31) * 4;   // K/V staging map
    const int nkv = (q0 + BQ_) / BKV_;                 // causal tile bound

    for (int t = 0; t < nkv; ++t) {
        const int k0 = t * BKV_;
        __syncthreads();
        #pragma unroll
        for (int p = 0; p < 4; ++p) {
            const int row = p * 8 + srow;
            *(float4*)&Ks[row][sc4] = *(const float4*)&Kb[(size_t)(k0 + row) * HD_ + sc4];
            *(float4*)&Vs[row][sc4] = *(const float4*)&Vb[(size_t)(k0 + row) * HD_ + sc4];
        }
        __syncthreads();

        // ---- S = Q K^T (partial over this lane's 32 dims) ----
        float sv[32];
        #pragma unroll
        for (int kc = 0; kc < BKV_; ++kc) {
            float a = 0.f;
            #pragma unroll
            for (int d8 = 0; d8 < 8; ++d8) {
                const float4 kv = *(const float4*)&Ks[kc][d8 * 16 + s4 * 4];
                a = fmaf(qr[d8 * 4 + 0], kv.x, a);
                a = fmaf(qr[d8 * 4 + 1], kv.y, a);
                a = fmaf(qr[d8 * 4 + 2], kv.z, a);
                a = fmaf(qr[d8 * 4 + 3], kv.w, a);
            }
            sv[kc] = a;
        }
        // butterfly-sum over the 4-lane row group -> full dot in every lane
        #pragma unroll
        for (int kc = 0; kc < BKV_; ++kc) {
            sv[kc] += __shfl_xor(sv[kc], 1);
            sv[kc] += __shfl_xor(sv[kc], 2);
        }

        // ---- online softmax (lane-local; all 4 lanes identical) ----
        float mloc = m_run;
        #pragma unroll
        for (int kc = 0; kc < BKV_; ++kc) {
            sv[kc] *= SCALE_;
            if (k0 + kc > qg) sv[kc] = -1e30f;   // causal mask
            mloc = fmaxf(mloc, sv[kc]);
        }
        const float alpha = __expf(m_run - mloc);
        m_run = mloc;
        float lsum = 0.f;
        #pragma unroll
        for (int kc = 0; kc < BKV_; ++kc) {
            sv[kc] = __expf(sv[kc] - mloc);
            lsum += sv[kc];
        }
        l_run = l_run * alpha + lsum;
        #pragma unroll
        for (int d = 0; d < 32; ++d) acc[d] *= alpha;

        // ---- O += P V ----
        #pragma unroll
        for (int k = 0; k < BKV_; ++k) {
            const float pk = sv[k];
            #pragma unroll
            for (int d8 = 0; d8 < 8; ++d8) {
                const float4 vv = *(const float4*)&Vs[k][d8 * 16 + s4 * 4];
                acc[d8 * 4 + 0] = fmaf(pk, vv.x, acc[d8 * 4 + 0]);
                acc[d8 * 4 + 1] = fmaf(pk, vv.y, acc[d8 * 4 + 1]);
                acc[d8 * 4 + 2] = fmaf(pk, vv.z, acc[d8 * 4 + 2]);
                acc[d8 * 4 + 3] = fmaf(pk, vv.w, acc[d8 * 4 + 3]);
            }
        }
    }

    // epilogue: O[b, q, h*HD + c(d)] = acc/l
    const float inv = 1.0f / l_run;
    const int b = bh >> 4, h = bh & (H_ - 1);
    float* op = Op + ((size_t)(b * L_ + qg)) * D_ + h * HD_;
    #pragma unroll
    for (int d8 = 0; d8 < 8; ++d8) {
        float4 w;
        w.x = acc[d8 * 4 + 0] * inv;
        w.y = acc[d8 * 4 + 1] * inv;
        w.z = acc[d8 * 4 + 2] * inv;
        w.w = acc[d8 * 4 + 3] * inv;
        *(float4*)&op[d8 * 16 + s4 * 4] = w;
    }
}

} // anonymous namespace

extern "C" void kernel_launch(void* const* d_in, const int* in_sizes, int n_in,
                              void* d_out, int out_size, void* d_ws, size_t ws_size,
                              hipStream_t stream)
{
    (void)in_sizes; (void)n_in; (void)out_size; (void)ws_size;

    const float* x    = (const float*)d_in[0];
    const float* cosp = (const float*)d_in[1];
    const float* sinp = (const float*)d_in[2];
    const float* Wqkv = (const float*)d_in[3];
    const float* bqkv = (const float*)d_in[4];
    const float* Wd   = (const float*)d_in[5];
    const float* bd   = (const float*)d_in[6];
    float* out = (float*)d_out;

    const size_t SZ = (size_t)B_ * H_ * L_ * HD_;   // 8M floats
    float* Qb = (float*)d_ws;
    float* Kb = Qb + SZ;
    float* Vb = Kb + SZ;
    float* Ob = Vb + SZ;   // total 128 MB of d_ws

    // 1) QKV GEMM + bias, scattered into (B,H,L,HD) Q/K/V
    {
        dim3 grid(6144 / 128, 4096 / 128);
        sgemm_k<1><<<grid, 256, 0, stream>>>(x, Wqkv, bqkv, nullptr,
                                             Qb, Kb, Vb, 4096, 6144, 2048);
    }
    // 2) RoPE in place on Q, K
    {
        const int total = B_ * H_ * L_ * 16;
        rope_k<<<total / 256, 256, 0, stream>>>(Qb, Kb, cosp, sinp);
    }
    // 3) causal flash attention -> Ob in (B,L,D) layout
    {
        dim3 grid(L_ / BQ_, B_ * H_);
        attn_k<<<grid, 256, 0, stream>>>(Qb, Kb, Vb, Ob);
    }
    // 4) output projection + bias
    {
        dim3 grid(2048 / 128, 4096 / 128);
        sgemm_k<0><<<grid, 256, 0, stream>>>(Ob, Wd, bd, out,
                                             nullptr, nullptr, nullptr,
                                             4096, 2048, 2048);
    }
}

// Round 3
// 3078.874 us; speedup vs baseline: 1.2531x; 1.2531x over previous
//
#include <hip/hip_runtime.h>
#include <cstdint>

// DecoderAttentionRotary: B=2, L=2048, D=2048, H=16, HD=128, R=32 (rotary dims)
// fp32 throughout. R2: attention register-blocked QR=2 (each ds_read_b128 feeds
// 8 FMAs instead of 4) -> flips attn from LDS-instr-bound to VALU-bound.
// Workspace layout (needs 128 MB): Q | K | V | O, each B*H*L*HD = 8M floats.

namespace {

constexpr int B_ = 2, L_ = 2048, D_ = 2048, H_ = 16, HD_ = 128, R_ = 32;
constexpr float SCALE_ = 0.08838834764831845f;   // 128^-0.5

// ---------------------------------------------------------------------------
// SGEMM: C[M,N] = A[M,K] * W[K,N] + bias[N]
// MODE 0: plain row-major write to Cout
// MODE 1: scatter into Q/K/V with (B,H,L,HD) layout (bias fused)
// Tile 128x128, BK=16, 256 threads, 8x8 per thread (split 4+4 rows/cols).
// ---------------------------------------------------------------------------
template <int MODE>
__global__ __launch_bounds__(256) void sgemm_k(
    const float* __restrict__ A, const float* __restrict__ W,
    const float* __restrict__ bias, float* __restrict__ Cout,
    float* __restrict__ Qp, float* __restrict__ Kp, float* __restrict__ Vp,
    int M, int N, int Kd)
{
    const int tid = threadIdx.x;
    const int tx = tid & 15, ty = tid >> 4;
    const int n0 = blockIdx.x * 128, m0 = blockIdx.y * 128;

    __shared__ float As[16][128];   // transposed: As[kk][m]
    __shared__ float Bs[16][128];   // natural:    Bs[kk][n]

    float acc[8][8] = {};

    const int arow = tid >> 1, au = (tid & 1) * 8;
    const int brow = tid >> 5, bcol = (tid & 31) * 4;

    const float* Ap = A + (size_t)(m0 + arow) * Kd + au;
    const float* Wp = W + (size_t)brow * N + n0 + bcol;

    float4 av0 = *(const float4*)Ap;
    float4 av1 = *(const float4*)(Ap + 4);
    float4 bv0 = *(const float4*)Wp;
    float4 bv1 = *(const float4*)(Wp + (size_t)8 * N);

    for (int k0 = 0; k0 < Kd; k0 += 16) {
        __syncthreads();
        As[au + 0][arow] = av0.x;
        As[au + 1][arow] = av0.y;
        As[au + 2][arow] = av0.z;
        As[au + 3][arow] = av0.w;
        As[au + 4][arow] = av1.x;
        As[au + 5][arow] = av1.y;
        As[au + 6][arow] = av1.z;
        As[au + 7][arow] = av1.w;
        *(float4*)&Bs[brow][bcol]     = bv0;
        *(float4*)&Bs[brow + 8][bcol] = bv1;
        __syncthreads();
        if (k0 + 16 < Kd) {        // prefetch next K-step
            av0 = *(const float4*)(Ap + k0 + 16);
            av1 = *(const float4*)(Ap + k0 + 20);
            bv0 = *(const float4*)(Wp + (size_t)(k0 + 16) * N);
            bv1 = *(const float4*)(Wp + (size_t)(k0 + 24) * N);
        }
        #pragma unroll
        for (int kk = 0; kk < 16; ++kk) {
            float a[8], b[8];
            *(float4*)&a[0] = *(const float4*)&As[kk][ty * 4];
            *(float4*)&a[4] = *(const float4*)&As[kk][64 + ty * 4];
            *(float4*)&b[0] = *(const float4*)&Bs[kk][tx * 4];
            *(float4*)&b[4] = *(const float4*)&Bs[kk][64 + tx * 4];
            #pragma unroll
            for (int i = 0; i < 8; ++i)
                #pragma unroll
                for (int j = 0; j < 8; ++j)
                    acc[i][j] = fmaf(a[i], b[j], acc[i][j]);
        }
    }

    #pragma unroll
    for (int j = 0; j < 8; ++j) {
        const int n = n0 + tx * 4 + ((j >> 2) * 64) + (j & 3);
        const float bn = bias[n];
        #pragma unroll
        for (int i = 0; i < 8; ++i) {
            const int m = m0 + ty * 4 + ((i >> 2) * 64) + (i & 3);
            const float v = acc[i][j] + bn;
            if (MODE == 0) {
                Cout[(size_t)m * N + n] = v;
            } else {
                const int b = m >> 11;          // m / L_
                const int l = m & (L_ - 1);
                const int h = n / 384;
                const int r = n - h * 384;
                const size_t base = ((size_t)(b * H_ + h) * L_ + l) * HD_;
                if (r < HD_)            Qp[base + r] = v;
                else if (r < 2 * HD_)   Kp[base + r - HD_] = v;
                else                    Vp[base + r - 2 * HD_] = v;
            }
        }
    }
}

// ---------------------------------------------------------------------------
// NeoX RoPE in place on Q and K, first R_=32 dims.
// ---------------------------------------------------------------------------
__global__ __launch_bounds__(256) void rope_k(
    float* __restrict__ Qp, float* __restrict__ Kp,
    const float* __restrict__ cosp, const float* __restrict__ sinp)
{
    const int idx = blockIdx.x * 256 + threadIdx.x;   // B*H*L*16 total
    const int j = idx & 15;
    const int bhl = idx >> 4;
    const int l = bhl & (L_ - 1);
    const float c = cosp[l * R_ + j];
    const float s = sinp[l * R_ + j];
    float* qp = Qp + (size_t)bhl * HD_;
    float* kp = Kp + (size_t)bhl * HD_;
    const float q1 = qp[j], q2 = qp[j + 16];
    qp[j]      = q1 * c - q2 * s;
    qp[j + 16] = q2 * c + q1 * s;
    const float k1 = kp[j], k2 = kp[j + 16];
    kp[j]      = k1 * c - k2 * s;
    kp[j + 16] = k2 * c + k1 * s;
}

// ---------------------------------------------------------------------------
// Flash attention (causal), fp32, register-blocked QR=2.
// Block: 128 threads (2 waves), BQ=64 rows: lane owns rows qloc and qloc+32.
// 4 lanes per row (s4), lane holds 32 interleaved dims c(d)=(d/4)*16+s4*4+d%4.
// Each Ks/Vs float4 read feeds 8 FMAs (2 rows x 4) -> VALU-bound, not LDS-bound.
// SCALE folded into Q registers at load. Softmax lane-local after 2-shfl
// butterfly. LDS: K+V tiles = 32 KB. ~220 VGPR -> 2 waves/SIMD.
// ---------------------------------------------------------------------------
constexpr int BQ_ = 64, BKV_ = 32;

__global__ __launch_bounds__(128, 2) void attn_k(
    const float* __restrict__ Qp, const float* __restrict__ Kp,
    const float* __restrict__ Vp, float* __restrict__ Op)
{
    const int tid = threadIdx.x;
    const int bh = blockIdx.y;                           // b*H + h
    const int qt = (int)gridDim.x - 1 - (int)blockIdx.x; // heavy tiles first
    const int q0 = qt * BQ_;
    const int qloc = tid >> 2;                           // 0..31
    const int s4 = tid & 3;
    const int qg0 = q0 + qloc;
    const int qg1 = qg0 + 32;

    __shared__ float Ks[BKV_][HD_];
    __shared__ float Vs[BKV_][HD_];

    const float* Qb = Qp + (size_t)bh * L_ * HD_;
    const float* Kb = Kp + (size_t)bh * L_ * HD_;
    const float* Vb = Vp + (size_t)bh * L_ * HD_;

    // Q rows -> registers (interleaved dims), SCALE pre-folded
    float qr0[32], qr1[32];
    #pragma unroll
    for (int d8 = 0; d8 < 8; ++d8) {
        const float4 t0 = *(const float4*)&Qb[(size_t)qg0 * HD_ + d8 * 16 + s4 * 4];
        const float4 t1 = *(const float4*)&Qb[(size_t)qg1 * HD_ + d8 * 16 + s4 * 4];
        qr0[d8 * 4 + 0] = t0.x * SCALE_; qr0[d8 * 4 + 1] = t0.y * SCALE_;
        qr0[d8 * 4 + 2] = t0.z * SCALE_; qr0[d8 * 4 + 3] = t0.w * SCALE_;
        qr1[d8 * 4 + 0] = t1.x * SCALE_; qr1[d8 * 4 + 1] = t1.y * SCALE_;
        qr1[d8 * 4 + 2] = t1.z * SCALE_; qr1[d8 * 4 + 3] = t1.w * SCALE_;
    }

    float m0 = -1e30f, l0 = 0.f, acc0[32] = {};
    float m1 = -1e30f, l1 = 0.f, acc1[32] = {};

    const int srow = tid >> 5, sc4 = (tid & 31) * 4;   // K/V staging map
    const int nkv = (q0 + BQ_) / BKV_;                 // causal tile bound

    for (int t = 0; t < nkv; ++t) {
        const int k0 = t * BKV_;
        __syncthreads();
        #pragma unroll
        for (int p = 0; p < 8; ++p) {
            const int row = p * 4 + srow;
            *(float4*)&Ks[row][sc4] = *(const float4*)&Kb[(size_t)(k0 + row) * HD_ + sc4];
            *(float4*)&Vs[row][sc4] = *(const float4*)&Vb[(size_t)(k0 + row) * HD_ + sc4];
        }
        __syncthreads();

        // ---- S = Q K^T (partial over this lane's 32 dims, 2 rows) ----
        float sv0[32], sv1[32];
        #pragma unroll
        for (int kc = 0; kc < BKV_; ++kc) {
            float a0 = 0.f, a1 = 0.f;
            #pragma unroll
            for (int d8 = 0; d8 < 8; ++d8) {
                const float4 kv = *(const float4*)&Ks[kc][d8 * 16 + s4 * 4];
                a0 = fmaf(qr0[d8 * 4 + 0], kv.x, a0);
                a1 = fmaf(qr1[d8 * 4 + 0], kv.x, a1);
                a0 = fmaf(qr0[d8 * 4 + 1], kv.y, a0);
                a1 = fmaf(qr1[d8 * 4 + 1], kv.y, a1);
                a0 = fmaf(qr0[d8 * 4 + 2], kv.z, a0);
                a1 = fmaf(qr1[d8 * 4 + 2], kv.z, a1);
                a0 = fmaf(qr0[d8 * 4 + 3], kv.w, a0);
                a1 = fmaf(qr1[d8 * 4 + 3], kv.w, a1);
            }
            sv0[kc] = a0; sv1[kc] = a1;
        }
        // butterfly-sum over the aligned 4-lane group -> full dot in every lane
        #pragma unroll
        for (int kc = 0; kc < BKV_; ++kc) {
            sv0[kc] += __shfl_xor(sv0[kc], 1);
            sv0[kc] += __shfl_xor(sv0[kc], 2);
            sv1[kc] += __shfl_xor(sv1[kc], 1);
            sv1[kc] += __shfl_xor(sv1[kc], 2);
        }

        // ---- online softmax (lane-local; 4 lanes per row identical) ----
        float ml0 = m0, ml1 = m1;
        #pragma unroll
        for (int kc = 0; kc < BKV_; ++kc) {
            if (k0 + kc > qg0) sv0[kc] = -1e30f;   // causal mask
            if (k0 + kc > qg1) sv1[kc] = -1e30f;
            ml0 = fmaxf(ml0, sv0[kc]);
            ml1 = fmaxf(ml1, sv1[kc]);
        }
        const float al0 = __expf(m0 - ml0);
        const float al1 = __expf(m1 - ml1);
        m0 = ml0; m1 = ml1;
        float ls0 = 0.f, ls1 = 0.f;
        #pragma unroll
        for (int kc = 0; kc < BKV_; ++kc) {
            sv0[kc] = __expf(sv0[kc] - ml0); ls0 += sv0[kc];
            sv1[kc] = __expf(sv1[kc] - ml1); ls1 += sv1[kc];
        }
        l0 = l0 * al0 + ls0;
        l1 = l1 * al1 + ls1;
        #pragma unroll
        for (int d = 0; d < 32; ++d) { acc0[d] *= al0; acc1[d] *= al1; }

        // ---- O += P V ----
        #pragma unroll
        for (int k = 0; k < BKV_; ++k) {
            const float p0 = sv0[k], p1 = sv1[k];
            #pragma unroll
            for (int d8 = 0; d8 < 8; ++d8) {
                const float4 vv = *(const float4*)&Vs[k][d8 * 16 + s4 * 4];
                acc0[d8 * 4 + 0] = fmaf(p0, vv.x, acc0[d8 * 4 + 0]);
                acc1[d8 * 4 + 0] = fmaf(p1, vv.x, acc1[d8 * 4 + 0]);
                acc0[d8 * 4 + 1] = fmaf(p0, vv.y, acc0[d8 * 4 + 1]);
                acc1[d8 * 4 + 1] = fmaf(p1, vv.y, acc1[d8 * 4 + 1]);
                acc0[d8 * 4 + 2] = fmaf(p0, vv.z, acc0[d8 * 4 + 2]);
                acc1[d8 * 4 + 2] = fmaf(p1, vv.z, acc1[d8 * 4 + 2]);
                acc0[d8 * 4 + 3] = fmaf(p0, vv.w, acc0[d8 * 4 + 3]);
                acc1[d8 * 4 + 3] = fmaf(p1, vv.w, acc1[d8 * 4 + 3]);
            }
        }
    }

    // epilogue: O[b, q, h*HD + c(d)] = acc/l for both rows
    const float inv0 = 1.0f / l0;
    const float inv1 = 1.0f / l1;
    const int b = bh >> 4, h = bh & (H_ - 1);
    float* op0 = Op + ((size_t)(b * L_ + qg0)) * D_ + h * HD_;
    float* op1 = Op + ((size_t)(b * L_ + qg1)) * D_ + h * HD_;
    #pragma unroll
    for (int d8 = 0; d8 < 8; ++d8) {
        float4 w0, w1;
        w0.x = acc0[d8 * 4 + 0] * inv0; w0.y = acc0[d8 * 4 + 1] * inv0;
        w0.z = acc0[d8 * 4 + 2] * inv0; w0.w = acc0[d8 * 4 + 3] * inv0;
        w1.x = acc1[d8 * 4 + 0] * inv1; w1.y = acc1[d8 * 4 + 1] * inv1;
        w1.z = acc1[d8 * 4 + 2] * inv1; w1.w = acc1[d8 * 4 + 3] * inv1;
        *(float4*)&op0[d8 * 16 + s4 * 4] = w0;
        *(float4*)&op1[d8 * 16 + s4 * 4] = w1;
    }
}

} // anonymous namespace

extern "C" void kernel_launch(void* const* d_in, const int* in_sizes, int n_in,
                              void* d_out, int out_size, void* d_ws, size_t ws_size,
                              hipStream_t stream)
{
    (void)in_sizes; (void)n_in; (void)out_size; (void)ws_size;

    const float* x    = (const float*)d_in[0];
    const float* cosp = (const float*)d_in[1];
    const float* sinp = (const float*)d_in[2];
    const float* Wqkv = (const float*)d_in[3];
    const float* bqkv = (const float*)d_in[4];
    const float* Wd   = (const float*)d_in[5];
    const float* bd   = (const float*)d_in[6];
    float* out = (float*)d_out;

    const size_t SZ = (size_t)B_ * H_ * L_ * HD_;   // 8M floats
    float* Qb = (float*)d_ws;
    float* Kb = Qb + SZ;
    float* Vb = Kb + SZ;
    float* Ob = Vb + SZ;   // total 128 MB of d_ws

    // 1) QKV GEMM + bias, scattered into (B,H,L,HD) Q/K/V
    {
        dim3 grid(6144 / 128, 4096 / 128);
        sgemm_k<1><<<grid, 256, 0, stream>>>(x, Wqkv, bqkv, nullptr,
                                             Qb, Kb, Vb, 4096, 6144, 2048);
    }
    // 2) RoPE in place on Q, K
    {
        const int total = B_ * H_ * L_ * 16;
        rope_k<<<total / 256, 256, 0, stream>>>(Qb, Kb, cosp, sinp);
    }
    // 3) causal flash attention -> Ob in (B,L,D) layout
    {
        dim3 grid(L_ / BQ_, B_ * H_);
        attn_k<<<grid, 128, 0, stream>>>(Qb, Kb, Vb, Ob);
    }
    // 4) output projection + bias
    {
        dim3 grid(2048 / 128, 4096 / 128);
        sgemm_k<0><<<grid, 256, 0, stream>>>(Ob, Wd, bd, out,
                                             nullptr, nullptr, nullptr,
                                             4096, 2048, 2048);
    }
}

// Round 5
// 1459.558 us; speedup vs baseline: 2.6434x; 2.1095x over previous
//
#include <hip/hip_runtime.h>
#include <cstdint>

// DecoderAttentionRotary: B=2, L=2048, D=2048, H=16, HD=128, R=32
// R5 (= R4 resubmitted; GPU timeout last round): GEMMs -> f16 MFMA
// (16x16x32, m97-structure: global_load_lds w16, swizzled packet LDS,
// 128x128x32 tile, 4 waves, 4x4 frags/wave). Attention unchanged from R3
// (passing) except f16 epilogue store.
// ws layout (121 MB): Qb|Kb|Vb f32 (96MB) | xh/Obh f16 (16.8MB, aliased) | WT f16 (8.4MB)

namespace {

constexpr int B_ = 2, L_ = 2048, D_ = 2048, H_ = 16, HD_ = 128, R_ = 32;
constexpr float SCALE_ = 0.08838834764831845f;   // 128^-0.5

typedef _Float16 f16;
typedef __attribute__((ext_vector_type(8))) _Float16 f16x8;
typedef __attribute__((ext_vector_type(4))) _Float16 f16x4;
typedef __attribute__((ext_vector_type(4))) float    f32x4;

__device__ __forceinline__ void gload_lds16(const void* g, void* l) {
    __builtin_amdgcn_global_load_lds(
        (const __attribute__((address_space(1))) void*)g,
        (__attribute__((address_space(3))) void*)l, 16, 0, 0);
}

// ---------------------------------------------------------------------------
// cast x f32 -> f16 (8.4M elems, float4/thread)
// ---------------------------------------------------------------------------
__global__ __launch_bounds__(256) void cast_x_k(const float* __restrict__ x,
                                                f16* __restrict__ xh)
{
    const size_t i = ((size_t)blockIdx.x * 256 + threadIdx.x) * 4;
    const float4 v = *(const float4*)&x[i];
    f16x4 h; h[0] = (f16)v.x; h[1] = (f16)v.y; h[2] = (f16)v.z; h[3] = (f16)v.w;
    *(f16x4*)&xh[i] = h;
}

// ---------------------------------------------------------------------------
// Transpose-cast W -> WT[n][k] f16 (k-contiguous for MFMA B staging).
// KIND 0: Wd (stride 2048, c = n). KIND 1..3: Wqkv Q/K/V column gather
//   (stride 6144, c = (n>>7)*384 + (KIND-1)*128 + (n&127)).
// 32x32 LDS tile, both phases coalesced.
// ---------------------------------------------------------------------------
template <int KIND>
__global__ __launch_bounds__(256) void transW_k(const float* __restrict__ W,
                                                f16* __restrict__ WT)
{
    const int t = threadIdx.x;
    const int n0 = blockIdx.x * 32, k0 = blockIdx.y * 32;
    const int stride = (KIND == 0) ? 2048 : 6144;
    const int c0 = (KIND == 0) ? n0 : ((n0 >> 7) * 384 + (KIND - 1) * 128 + (n0 & 127));

    __shared__ float tl[32][33];

    const int kr = t >> 3, cc = (t & 7) * 4;
    const float4 v = *(const float4*)&W[(size_t)(k0 + kr) * stride + c0 + cc];
    tl[kr][cc + 0] = v.x; tl[kr][cc + 1] = v.y;
    tl[kr][cc + 2] = v.z; tl[kr][cc + 3] = v.w;
    __syncthreads();

    const int nr = t >> 3, kk = (t & 7) * 4;
    f16x4 w;
    w[0] = (f16)tl[kk + 0][nr]; w[1] = (f16)tl[kk + 1][nr];
    w[2] = (f16)tl[kk + 2][nr]; w[3] = (f16)tl[kk + 3][nr];
    *(f16x4*)&WT[(size_t)(n0 + nr) * 2048 + k0 + kk] = w;
}

// ---------------------------------------------------------------------------
// f16 MFMA GEMM: C[4096][2048] = A[4096][2048] * WT[2048][2048]^T (+bias)
// A, WT both row-major k-contiguous f16. Tile 128x128, BK=32, 256 thr (4 waves
// 2x2), wave = 64x64 = 4x4 frags of 16x16x32. Accum fp32.
// LDS: packet layout — packet(m,kc) (16B = 8 f16, k-contig) at byte
//   m*64 + ((kc ^ ((m>>1)&3))*16); staged via global_load_lds w16 with
//   pre-swizzled global source (slot t -> m=t>>2, kc=(t&3)^((t>>3)&3)).
// Conflict-free for staging writes and ds_read_b128 fragment reads.
// MODE 0: out + bd. MODE 1/2/3: scatter to Q/K/V (B,H,L,HD) + bqkv gather.
// ---------------------------------------------------------------------------
template <int MODE>
__global__ __launch_bounds__(256) void hgemm_k(
    const f16* __restrict__ A, const f16* __restrict__ Bt,
    const float* __restrict__ bias, float* __restrict__ C)
{
    const int tid  = threadIdx.x;
    const int lane = tid & 63;
    const int wid  = tid >> 6;
    const int n0 = blockIdx.x * 128, m0 = blockIdx.y * 128;
    const int wm = (wid >> 1) * 64, wn = (wid & 1) * 64;

    __shared__ uint4 ldsb[1024];              // 16 KB: A 8 KB | B 8 KB
    char* AsB = (char*)ldsb;
    char* BsB = AsB + 8192;

    // staging: wave issues insts j = 2*wid, 2*wid+1 for A and for B
    int gOffA[2], gOffB[2];                   // element offsets (f16)
    char *ldsA[2], *ldsB[2];
    #pragma unroll
    for (int i = 0; i < 2; ++i) {
        const int j = 2 * wid + i;
        const int t = j * 64 + lane;
        const int m  = t >> 2;
        const int kc = (t & 3) ^ ((t >> 3) & 3);
        gOffA[i] = (m0 + m) * 2048 + kc * 8;
        gOffB[i] = (n0 + m) * 2048 + kc * 8;
        ldsA[i] = AsB + j * 1024;
        ldsB[i] = BsB + j * 1024;
    }

    // fragment read bases (swizzle bits constant per lane; frag step = 1024 B)
    const int rowa = wm + (lane & 15);
    const int rowb = wn + (lane & 15);
    const int aBase = rowa * 64 + (((lane >> 4) ^ ((rowa >> 1) & 3)) << 4);
    const int bBase = rowb * 64 + (((lane >> 4) ^ ((rowb >> 1) & 3)) << 4);

    f32x4 acc[4][4];
    #pragma unroll
    for (int i = 0; i < 4; ++i)
        #pragma unroll
        for (int j = 0; j < 4; ++j)
            acc[i][j] = (f32x4){0.f, 0.f, 0.f, 0.f};

    for (int k0 = 0; k0 < 2048; k0 += 32) {
        __syncthreads();                       // previous compute done
        #pragma unroll
        for (int i = 0; i < 2; ++i) {
            gload_lds16(A  + (size_t)gOffA[i] + k0, ldsA[i]);
            gload_lds16(Bt + (size_t)gOffB[i] + k0, ldsB[i]);
        }
        __syncthreads();                       // vmcnt(0) drain + barrier

        f16x8 af[4], bf[4];
        #pragma unroll
        for (int mf = 0; mf < 4; ++mf) af[mf] = *(const f16x8*)(AsB + aBase + mf * 1024);
        #pragma unroll
        for (int nf = 0; nf < 4; ++nf) bf[nf] = *(const f16x8*)(BsB + bBase + nf * 1024);
        #pragma unroll
        for (int mf = 0; mf < 4; ++mf)
            #pragma unroll
            for (int nf = 0; nf < 4; ++nf)
                acc[mf][nf] = __builtin_amdgcn_mfma_f32_16x16x32_f16(
                    af[mf], bf[nf], acc[mf][nf], 0, 0, 0);
    }

    // epilogue: D row = (lane>>4)*4 + r, col = lane&15 (m89-verified layout)
    #pragma unroll
    for (int nf = 0; nf < 4; ++nf) {
        const int col = n0 + wn + nf * 16 + (lane & 15);
        float bn;
        if (MODE == 0) bn = bias[col];
        else           bn = bias[(col >> 7) * 384 + (MODE - 1) * 128 + (col & 127)];
        #pragma unroll
        for (int mf = 0; mf < 4; ++mf) {
            const int rbase = m0 + wm + mf * 16 + ((lane >> 4) << 2);
            #pragma unroll
            for (int r = 0; r < 4; ++r) {
                const float v = acc[mf][nf][r] + bn;
                const int m = rbase + r;
                if (MODE == 0) {
                    C[(size_t)m * 2048 + col] = v;
                } else {
                    const int b = m >> 11, l = m & (L_ - 1);
                    const int h = col >> 7, d = col & 127;
                    C[((size_t)(b * H_ + h) * L_ + l) * HD_ + d] = v;
                }
            }
        }
    }
}

// ---------------------------------------------------------------------------
// NeoX RoPE in place on Q and K, first R_=32 dims (unchanged, passing).
// ---------------------------------------------------------------------------
__global__ __launch_bounds__(256) void rope_k(
    float* __restrict__ Qp, float* __restrict__ Kp,
    const float* __restrict__ cosp, const float* __restrict__ sinp)
{
    const int idx = blockIdx.x * 256 + threadIdx.x;
    const int j = idx & 15;
    const int bhl = idx >> 4;
    const int l = bhl & (L_ - 1);
    const float c = cosp[l * R_ + j];
    const float s = sinp[l * R_ + j];
    float* qp = Qp + (size_t)bhl * HD_;
    float* kp = Kp + (size_t)bhl * HD_;
    const float q1 = qp[j], q2 = qp[j + 16];
    qp[j]      = q1 * c - q2 * s;
    qp[j + 16] = q2 * c + q1 * s;
    const float k1 = kp[j], k2 = kp[j + 16];
    kp[j]      = k1 * c - k2 * s;
    kp[j + 16] = k2 * c + k1 * s;
}

// ---------------------------------------------------------------------------
// Flash attention (causal), fp32, QR=2 — identical to R3 (passing) except the
// epilogue stores f16 into Obh (proj GEMM input).
// ---------------------------------------------------------------------------
constexpr int BQ_ = 64, BKV_ = 32;

__global__ __launch_bounds__(128, 2) void attn_k(
    const float* __restrict__ Qp, const float* __restrict__ Kp,
    const float* __restrict__ Vp, f16* __restrict__ Oh)
{
    const int tid = threadIdx.x;
    const int bh = blockIdx.y;
    const int qt = (int)gridDim.x - 1 - (int)blockIdx.x;
    const int q0 = qt * BQ_;
    const int qloc = tid >> 2;
    const int s4 = tid & 3;
    const int qg0 = q0 + qloc;
    const int qg1 = qg0 + 32;

    __shared__ float Ks[BKV_][HD_];
    __shared__ float Vs[BKV_][HD_];

    const float* Qb = Qp + (size_t)bh * L_ * HD_;
    const float* Kb = Kp + (size_t)bh * L_ * HD_;
    const float* Vb = Vp + (size_t)bh * L_ * HD_;

    float qr0[32], qr1[32];
    #pragma unroll
    for (int d8 = 0; d8 < 8; ++d8) {
        const float4 t0 = *(const float4*)&Qb[(size_t)qg0 * HD_ + d8 * 16 + s4 * 4];
        const float4 t1 = *(const float4*)&Qb[(size_t)qg1 * HD_ + d8 * 16 + s4 * 4];
        qr0[d8 * 4 + 0] = t0.x * SCALE_; qr0[d8 * 4 + 1] = t0.y * SCALE_;
        qr0[d8 * 4 + 2] = t0.z * SCALE_; qr0[d8 * 4 + 3] = t0.w * SCALE_;
        qr1[d8 * 4 + 0] = t1.x * SCALE_; qr1[d8 * 4 + 1] = t1.y * SCALE_;
        qr1[d8 * 4 + 2] = t1.z * SCALE_; qr1[d8 * 4 + 3] = t1.w * SCALE_;
    }

    float m0 = -1e30f, l0 = 0.f, acc0[32] = {};
    float m1 = -1e30f, l1 = 0.f, acc1[32] = {};

    const int srow = tid >> 5, sc4 = (tid & 31) * 4;
    const int nkv = (q0 + BQ_) / BKV_;

    for (int t = 0; t < nkv; ++t) {
        const int k0 = t * BKV_;
        __syncthreads();
        #pragma unroll
        for (int p = 0; p < 8; ++p) {
            const int row = p * 4 + srow;
            *(float4*)&Ks[row][sc4] = *(const float4*)&Kb[(size_t)(k0 + row) * HD_ + sc4];
            *(float4*)&Vs[row][sc4] = *(const float4*)&Vb[(size_t)(k0 + row) * HD_ + sc4];
        }
        __syncthreads();

        float sv0[32], sv1[32];
        #pragma unroll
        for (int kc = 0; kc < BKV_; ++kc) {
            float a0 = 0.f, a1 = 0.f;
            #pragma unroll
            for (int d8 = 0; d8 < 8; ++d8) {
                const float4 kv = *(const float4*)&Ks[kc][d8 * 16 + s4 * 4];
                a0 = fmaf(qr0[d8 * 4 + 0], kv.x, a0);
                a1 = fmaf(qr1[d8 * 4 + 0], kv.x, a1);
                a0 = fmaf(qr0[d8 * 4 + 1], kv.y, a0);
                a1 = fmaf(qr1[d8 * 4 + 1], kv.y, a1);
                a0 = fmaf(qr0[d8 * 4 + 2], kv.z, a0);
                a1 = fmaf(qr1[d8 * 4 + 2], kv.z, a1);
                a0 = fmaf(qr0[d8 * 4 + 3], kv.w, a0);
                a1 = fmaf(qr1[d8 * 4 + 3], kv.w, a1);
            }
            sv0[kc] = a0; sv1[kc] = a1;
        }
        #pragma unroll
        for (int kc = 0; kc < BKV_; ++kc) {
            sv0[kc] += __shfl_xor(sv0[kc], 1);
            sv0[kc] += __shfl_xor(sv0[kc], 2);
            sv1[kc] += __shfl_xor(sv1[kc], 1);
            sv1[kc] += __shfl_xor(sv1[kc], 2);
        }

        float ml0 = m0, ml1 = m1;
        #pragma unroll
        for (int kc = 0; kc < BKV_; ++kc) {
            if (k0 + kc > qg0) sv0[kc] = -1e30f;
            if (k0 + kc > qg1) sv1[kc] = -1e30f;
            ml0 = fmaxf(ml0, sv0[kc]);
            ml1 = fmaxf(ml1, sv1[kc]);
        }
        const float al0 = __expf(m0 - ml0);
        const float al1 = __expf(m1 - ml1);
        m0 = ml0; m1 = ml1;
        float ls0 = 0.f, ls1 = 0.f;
        #pragma unroll
        for (int kc = 0; kc < BKV_; ++kc) {
            sv0[kc] = __expf(sv0[kc] - ml0); ls0 += sv0[kc];
            sv1[kc] = __expf(sv1[kc] - ml1); ls1 += sv1[kc];
        }
        l0 = l0 * al0 + ls0;
        l1 = l1 * al1 + ls1;
        #pragma unroll
        for (int d = 0; d < 32; ++d) { acc0[d] *= al0; acc1[d] *= al1; }

        #pragma unroll
        for (int k = 0; k < BKV_; ++k) {
            const float p0 = sv0[k], p1 = sv1[k];
            #pragma unroll
            for (int d8 = 0; d8 < 8; ++d8) {
                const float4 vv = *(const float4*)&Vs[k][d8 * 16 + s4 * 4];
                acc0[d8 * 4 + 0] = fmaf(p0, vv.x, acc0[d8 * 4 + 0]);
                acc1[d8 * 4 + 0] = fmaf(p1, vv.x, acc1[d8 * 4 + 0]);
                acc0[d8 * 4 + 1] = fmaf(p0, vv.y, acc0[d8 * 4 + 1]);
                acc1[d8 * 4 + 1] = fmaf(p1, vv.y, acc1[d8 * 4 + 1]);
                acc0[d8 * 4 + 2] = fmaf(p0, vv.z, acc0[d8 * 4 + 2]);
                acc1[d8 * 4 + 2] = fmaf(p1, vv.z, acc1[d8 * 4 + 2]);
                acc0[d8 * 4 + 3] = fmaf(p0, vv.w, acc0[d8 * 4 + 3]);
                acc1[d8 * 4 + 3] = fmaf(p1, vv.w, acc1[d8 * 4 + 3]);
            }
        }
    }

    const float inv0 = 1.0f / l0;
    const float inv1 = 1.0f / l1;
    const int b = bh >> 4, h = bh & (H_ - 1);
    f16* op0 = Oh + ((size_t)(b * L_ + qg0)) * D_ + h * HD_;
    f16* op1 = Oh + ((size_t)(b * L_ + qg1)) * D_ + h * HD_;
    #pragma unroll
    for (int d8 = 0; d8 < 8; ++d8) {
        f16x4 w0, w1;
        w0[0] = (f16)(acc0[d8 * 4 + 0] * inv0); w0[1] = (f16)(acc0[d8 * 4 + 1] * inv0);
        w0[2] = (f16)(acc0[d8 * 4 + 2] * inv0); w0[3] = (f16)(acc0[d8 * 4 + 3] * inv0);
        w1[0] = (f16)(acc1[d8 * 4 + 0] * inv1); w1[1] = (f16)(acc1[d8 * 4 + 1] * inv1);
        w1[2] = (f16)(acc1[d8 * 4 + 2] * inv1); w1[3] = (f16)(acc1[d8 * 4 + 3] * inv1);
        *(f16x4*)&op0[d8 * 16 + s4 * 4] = w0;
        *(f16x4*)&op1[d8 * 16 + s4 * 4] = w1;
    }
}

} // anonymous namespace

extern "C" void kernel_launch(void* const* d_in, const int* in_sizes, int n_in,
                              void* d_out, int out_size, void* d_ws, size_t ws_size,
                              hipStream_t stream)
{
    (void)in_sizes; (void)n_in; (void)out_size; (void)ws_size;

    const float* x    = (const float*)d_in[0];
    const float* cosp = (const float*)d_in[1];
    const float* sinp = (const float*)d_in[2];
    const float* Wqkv = (const float*)d_in[3];
    const float* bqkv = (const float*)d_in[4];
    const float* Wd   = (const float*)d_in[5];
    const float* bd   = (const float*)d_in[6];
    float* out = (float*)d_out;

    const size_t SZ = (size_t)B_ * H_ * L_ * HD_;   // 8.39M elems
    float* Qb = (float*)d_ws;
    float* Kb = Qb + SZ;
    float* Vb = Kb + SZ;
    f16*   xh = (f16*)(Vb + SZ);      // 16.8 MB
    f16*   Oh = xh;                   // alias: xh dead after QKV GEMMs
    f16*   WT = xh + SZ;              // 8.4 MB, reused per slice + Wd
    // peak ws: 96 + 16.8 + 8.4 = 121.2 MB

    const dim3 gT(64, 64), gG(16, 32);

    cast_x_k<<<8192, 256, 0, stream>>>(x, xh);

    // QKV slices: transpose Wqkv column-gather -> WT, then MFMA GEMM scatter
    transW_k<1><<<gT, 256, 0, stream>>>(Wqkv, WT);
    hgemm_k<1><<<gG, 256, 0, stream>>>(xh, WT, bqkv, Qb);
    transW_k<2><<<gT, 256, 0, stream>>>(Wqkv, WT);
    hgemm_k<2><<<gG, 256, 0, stream>>>(xh, WT, bqkv, Kb);
    transW_k<3><<<gT, 256, 0, stream>>>(Wqkv, WT);
    hgemm_k<3><<<gG, 256, 0, stream>>>(xh, WT, bqkv, Vb);

    rope_k<<<4096, 256, 0, stream>>>(Qb, Kb, cosp, sinp);

    attn_k<<<dim3(L_ / BQ_, B_ * H_), 128, 0, stream>>>(Qb, Kb, Vb, Oh);

    transW_k<0><<<gT, 256, 0, stream>>>(Wd, WT);
    hgemm_k<0><<<gG, 256, 0, stream>>>(Oh, WT, bd, out);
}

// Round 6
// 438.163 us; speedup vs baseline: 8.8053x; 3.3311x over previous
//
#include <hip/hip_runtime.h>
#include <cstdint>

// DecoderAttentionRotary: B=2, L=2048, D=2048, H=16, HD=128, R=32
// R6: f16 end-to-end. GEMMs f16 MFMA (unchanged m97-structure). Attention
// rewritten on mfma_f32_16x16x32_f16: 4 waves x 16 q-rows, BKV=64,
// K linear-LDS via pre-swizzled global_load_lds, V reg-transposed LDS,
// P via per-wave swizzled LDS round-trip. Causal pairing (qt, 31-qt):
// every block = exactly 33 KV tiles (perfect balance), grid 512.
// ws (84 MB): Qh|Kh|Vh f16 | xh/Oh f16 (alias) | WT f16.

namespace {

constexpr int B_ = 2, L_ = 2048, D_ = 2048, H_ = 16, HD_ = 128, R_ = 32;
constexpr float SCALE_ = 0.08838834764831845f;   // 128^-0.5

typedef _Float16 f16;
typedef __attribute__((ext_vector_type(8))) _Float16 f16x8;
typedef __attribute__((ext_vector_type(4))) _Float16 f16x4;
typedef __attribute__((ext_vector_type(8))) unsigned short u16x8;
typedef __attribute__((ext_vector_type(4))) float    f32x4;

__device__ __forceinline__ void gload_lds16(const void* g, void* l) {
    __builtin_amdgcn_global_load_lds(
        (const __attribute__((address_space(1))) void*)g,
        (__attribute__((address_space(3))) void*)l, 16, 0, 0);
}

// ---------------------------------------------------------------------------
// cast x f32 -> f16
// ---------------------------------------------------------------------------
__global__ __launch_bounds__(256) void cast_x_k(const float* __restrict__ x,
                                                f16* __restrict__ xh)
{
    const size_t i = ((size_t)blockIdx.x * 256 + threadIdx.x) * 4;
    const float4 v = *(const float4*)&x[i];
    f16x4 h; h[0] = (f16)v.x; h[1] = (f16)v.y; h[2] = (f16)v.z; h[3] = (f16)v.w;
    *(f16x4*)&xh[i] = h;
}

// ---------------------------------------------------------------------------
// Transpose-cast W -> WT[n][k] f16. KIND 0: Wd. KIND 1..3: Wqkv Q/K/V gather.
// ---------------------------------------------------------------------------
template <int KIND>
__global__ __launch_bounds__(256) void transW_k(const float* __restrict__ W,
                                                f16* __restrict__ WT)
{
    const int t = threadIdx.x;
    const int n0 = blockIdx.x * 32, k0 = blockIdx.y * 32;
    const int stride = (KIND == 0) ? 2048 : 6144;
    const int c0 = (KIND == 0) ? n0 : ((n0 >> 7) * 384 + (KIND - 1) * 128 + (n0 & 127));

    __shared__ float tl[32][33];

    const int kr = t >> 3, cc = (t & 7) * 4;
    const float4 v = *(const float4*)&W[(size_t)(k0 + kr) * stride + c0 + cc];
    tl[kr][cc + 0] = v.x; tl[kr][cc + 1] = v.y;
    tl[kr][cc + 2] = v.z; tl[kr][cc + 3] = v.w;
    __syncthreads();

    const int nr = t >> 3, kk = (t & 7) * 4;
    f16x4 w;
    w[0] = (f16)tl[kk + 0][nr]; w[1] = (f16)tl[kk + 1][nr];
    w[2] = (f16)tl[kk + 2][nr]; w[3] = (f16)tl[kk + 3][nr];
    *(f16x4*)&WT[(size_t)(n0 + nr) * 2048 + k0 + kk] = w;
}

// ---------------------------------------------------------------------------
// f16 MFMA GEMM (m97-structure, passing in R5). MODE 0: float out + bd.
// MODE 1/2/3: f16 scatter to Q/K/V (B,H,L,HD) + bqkv gather.
// ---------------------------------------------------------------------------
template <int MODE>
__global__ __launch_bounds__(256) void hgemm_k(
    const f16* __restrict__ A, const f16* __restrict__ Bt,
    const float* __restrict__ bias, void* __restrict__ C)
{
    const int tid  = threadIdx.x;
    const int lane = tid & 63;
    const int wid  = tid >> 6;
    const int n0 = blockIdx.x * 128, m0 = blockIdx.y * 128;
    const int wm = (wid >> 1) * 64, wn = (wid & 1) * 64;

    __shared__ uint4 ldsb[1024];              // 16 KB: A 8 KB | B 8 KB
    char* AsB = (char*)ldsb;
    char* BsB = AsB + 8192;

    int gOffA[2], gOffB[2];
    char *ldsA[2], *ldsB[2];
    #pragma unroll
    for (int i = 0; i < 2; ++i) {
        const int j = 2 * wid + i;
        const int t = j * 64 + lane;
        const int m  = t >> 2;
        const int kc = (t & 3) ^ ((t >> 3) & 3);
        gOffA[i] = (m0 + m) * 2048 + kc * 8;
        gOffB[i] = (n0 + m) * 2048 + kc * 8;
        ldsA[i] = AsB + j * 1024;
        ldsB[i] = BsB + j * 1024;
    }

    const int rowa = wm + (lane & 15);
    const int rowb = wn + (lane & 15);
    const int aBase = rowa * 64 + (((lane >> 4) ^ ((rowa >> 1) & 3)) << 4);
    const int bBase = rowb * 64 + (((lane >> 4) ^ ((rowb >> 1) & 3)) << 4);

    f32x4 acc[4][4];
    #pragma unroll
    for (int i = 0; i < 4; ++i)
        #pragma unroll
        for (int j = 0; j < 4; ++j)
            acc[i][j] = (f32x4){0.f, 0.f, 0.f, 0.f};

    for (int k0 = 0; k0 < 2048; k0 += 32) {
        __syncthreads();
        #pragma unroll
        for (int i = 0; i < 2; ++i) {
            gload_lds16(A  + (size_t)gOffA[i] + k0, ldsA[i]);
            gload_lds16(Bt + (size_t)gOffB[i] + k0, ldsB[i]);
        }
        __syncthreads();

        f16x8 af[4], bf[4];
        #pragma unroll
        for (int mf = 0; mf < 4; ++mf) af[mf] = *(const f16x8*)(AsB + aBase + mf * 1024);
        #pragma unroll
        for (int nf = 0; nf < 4; ++nf) bf[nf] = *(const f16x8*)(BsB + bBase + nf * 1024);
        #pragma unroll
        for (int mf = 0; mf < 4; ++mf)
            #pragma unroll
            for (int nf = 0; nf < 4; ++nf)
                acc[mf][nf] = __builtin_amdgcn_mfma_f32_16x16x32_f16(
                    af[mf], bf[nf], acc[mf][nf], 0, 0, 0);
    }

    #pragma unroll
    for (int nf = 0; nf < 4; ++nf) {
        const int col = n0 + wn + nf * 16 + (lane & 15);
        float bn;
        if (MODE == 0) bn = bias[col];
        else           bn = bias[(col >> 7) * 384 + (MODE - 1) * 128 + (col & 127)];
        #pragma unroll
        for (int mf = 0; mf < 4; ++mf) {
            const int rbase = m0 + wm + mf * 16 + ((lane >> 4) << 2);
            #pragma unroll
            for (int r = 0; r < 4; ++r) {
                const float v = acc[mf][nf][r] + bn;
                const int m = rbase + r;
                if (MODE == 0) {
                    ((float*)C)[(size_t)m * 2048 + col] = v;
                } else {
                    const int b = m >> 11, l = m & (L_ - 1);
                    const int h = col >> 7, d = col & 127;
                    ((f16*)C)[((size_t)(b * H_ + h) * L_ + l) * HD_ + d] = (f16)v;
                }
            }
        }
    }
}

// ---------------------------------------------------------------------------
// NeoX RoPE in place on f16 Q and K, first R_=32 dims.
// ---------------------------------------------------------------------------
__global__ __launch_bounds__(256) void rope_k(
    f16* __restrict__ Qp, f16* __restrict__ Kp,
    const float* __restrict__ cosp, const float* __restrict__ sinp)
{
    const int idx = blockIdx.x * 256 + threadIdx.x;
    const int j = idx & 15;
    const int bhl = idx >> 4;
    const int l = bhl & (L_ - 1);
    const float c = cosp[l * R_ + j];
    const float s = sinp[l * R_ + j];
    f16* qp = Qp + (size_t)bhl * HD_;
    f16* kp = Kp + (size_t)bhl * HD_;
    const float q1 = (float)qp[j], q2 = (float)qp[j + 16];
    qp[j]      = (f16)(q1 * c - q2 * s);
    qp[j + 16] = (f16)(q2 * c + q1 * s);
    const float k1 = (float)kp[j], k2 = (float)kp[j + 16];
    kp[j]      = (f16)(k1 * c - k2 * s);
    kp[j + 16] = (f16)(k2 * c + k1 * s);
}

// ---------------------------------------------------------------------------
// MFMA flash attention (causal, f16 in / f16 out, fp32 accum).
// Block 256 thr = 4 waves x 16 q-rows; BKV=64; two q-tiles (qt, 31-qt)
// per block -> 33 KV tiles per block, perfectly balanced. Grid (16, 32).
// LDS 40 KB: Ksh[64][128] (pre-swizzled gload_lds, chunk^=row&7),
//            Vt[128][64]  (reg-transposed, k-pair b32 writes, chunk^=d&7),
//            P[4][16][64] (per-wave, chunk^=q&7).
// ---------------------------------------------------------------------------
__global__ __launch_bounds__(256) void attn2_k(
    const f16* __restrict__ Qh, const f16* __restrict__ Kh,
    const f16* __restrict__ Vh, f16* __restrict__ Oh)
{
    const int tid  = threadIdx.x;
    const int lane = tid & 63;
    const int wid  = tid >> 6;
    const int qtb  = blockIdx.x;    // 0..15
    const int bh   = blockIdx.y;    // 0..31
    const int lr   = lane >> 4;     // 0..3
    const int lc   = lane & 15;
    const int l7   = lane & 7;

    __shared__ f16 Ksh[64 * 128];
    __shared__ f16 Vts[128 * 64];
    __shared__ f16 Pls[4][16 * 64];

    const f16* Qb = Qh + (size_t)bh * (L_ * HD_);
    const f16* Kb = Kh + (size_t)bh * (L_ * HD_);
    const f16* Vb = Vh + (size_t)bh * (L_ * HD_);
    char* const KshB = (char*)Ksh;
    char* const VtsB = (char*)Vts;
    char* const PwB  = (char*)(&Pls[wid][0]);

    #pragma unroll
    for (int ph = 0; ph < 2; ++ph) {
        const int qe  = ph ? (31 - qtb) : qtb;
        const int q0  = qe * 64;
        const int wq0 = q0 + wid * 16;

        // Q A-frags: row = wq0 + lc, d = j*32 + lr*8 .. +8
        f16x8 qa[4];
        #pragma unroll
        for (int j = 0; j < 4; ++j)
            qa[j] = *(const f16x8*)&Qb[(size_t)(wq0 + lc) * HD_ + j * 32 + lr * 8];

        f32x4 of[8];
        #pragma unroll
        for (int ds = 0; ds < 8; ++ds) of[ds] = (f32x4){0.f, 0.f, 0.f, 0.f};
        float m_run[4] = {-1e30f, -1e30f, -1e30f, -1e30f};
        float l_run[4] = {0.f, 0.f, 0.f, 0.f};

        const int nkv = qe + 1;
        for (int t = 0; t < nkv; ++t) {
            const int k0 = t * 64;
            __syncthreads();
            // ---- stage K: linear LDS, pre-swizzled global source ----
            #pragma unroll
            for (int i = 0; i < 4; ++i) {
                const int slot = i * 256 + tid;
                const int row = slot >> 4, cch = slot & 15;
                const f16* src = Kb + (size_t)(k0 + row) * HD_ + (cch ^ (row & 7)) * 8;
                char* dst = KshB + (i * 256 + wid * 64) * 16;   // wave-uniform
                gload_lds16(src, dst);
            }
            // ---- stage V transposed: Vt[d][k], k-pair packed b32 ----
            #pragma unroll
            for (int rnd = 0; rnd < 2; ++rnd) {
                const int pc = rnd * 256 + tid;
                const int kp = pc & 31, dc = pc >> 5;
                const f16x8 va = *(const f16x8*)&Vb[(size_t)(k0 + 2 * kp) * HD_ + dc * 8];
                const f16x8 vb2 = *(const f16x8*)&Vb[(size_t)(k0 + 2 * kp + 1) * HD_ + dc * 8];
                const u16x8 au = *(const u16x8*)&va;
                const u16x8 bu = *(const u16x8*)&vb2;
                #pragma unroll
                for (int i = 0; i < 8; ++i) {
                    const int d = dc * 8 + i;
                    const unsigned int pv = (unsigned)au[i] | ((unsigned)bu[i] << 16);
                    *(unsigned int*)(VtsB + d * 128 + ((4 * kp) ^ ((d & 7) << 4))) = pv;
                }
            }
            __syncthreads();

            // ---- S = Q K^T ----
            f32x4 sacc[4];
            #pragma unroll
            for (int ks = 0; ks < 4; ++ks) sacc[ks] = (f32x4){0.f, 0.f, 0.f, 0.f};
            #pragma unroll
            for (int ks = 0; ks < 4; ++ks) {
                const int rowk = ks * 16 + lc;
                f16x8 kb[4];
                #pragma unroll
                for (int j = 0; j < 4; ++j)
                    kb[j] = *(const f16x8*)(KshB + rowk * 256 + (((j * 4 + lr) ^ l7) * 16));
                #pragma unroll
                for (int j = 0; j < 4; ++j)
                    sacc[ks] = __builtin_amdgcn_mfma_f32_16x16x32_f16(
                        qa[j], kb[j], sacc[ks], 0, 0, 0);
            }
            // scale (+ causal mask on diagonal tile)
            #pragma unroll
            for (int ks = 0; ks < 4; ++ks)
                #pragma unroll
                for (int r = 0; r < 4; ++r) sacc[ks][r] *= SCALE_;
            if (t == qe) {
                #pragma unroll
                for (int ks = 0; ks < 4; ++ks)
                    #pragma unroll
                    for (int r = 0; r < 4; ++r)
                        if (k0 + ks * 16 + lc > wq0 + lr * 4 + r) sacc[ks][r] = -1e30f;
            }
            // ---- online softmax (rows spread over 16-lane groups) ----
            float mx[4];
            #pragma unroll
            for (int r = 0; r < 4; ++r)
                mx[r] = fmaxf(fmaxf(sacc[0][r], sacc[1][r]),
                              fmaxf(sacc[2][r], sacc[3][r]));
            #pragma unroll
            for (int msk = 1; msk <= 8; msk <<= 1)
                #pragma unroll
                for (int r = 0; r < 4; ++r)
                    mx[r] = fmaxf(mx[r], __shfl_xor(mx[r], msk));
            float alpha[4];
            #pragma unroll
            for (int r = 0; r < 4; ++r) {
                mx[r] = fmaxf(mx[r], m_run[r]);
                alpha[r] = __expf(m_run[r] - mx[r]);
                m_run[r] = mx[r];
            }
            float ls[4] = {0.f, 0.f, 0.f, 0.f};
            #pragma unroll
            for (int ks = 0; ks < 4; ++ks)
                #pragma unroll
                for (int r = 0; r < 4; ++r) {
                    const float p = __expf(sacc[ks][r] - m_run[r]);
                    ls[r] += p;
                    sacc[ks][r] = p;
                }
            // write P to per-wave LDS (row q=lr*4+r, col k=ks*16+lc, swizzled)
            #pragma unroll
            for (int ks = 0; ks < 4; ++ks)
                #pragma unroll
                for (int r = 0; r < 4; ++r) {
                    const int q = lr * 4 + r;
                    *(f16*)(PwB + q * 128 + ((ks * 32 + lc * 2) ^ ((q & 7) << 4))) =
                        (f16)sacc[ks][r];
                }
            #pragma unroll
            for (int msk = 1; msk <= 8; msk <<= 1)
                #pragma unroll
                for (int r = 0; r < 4; ++r) ls[r] += __shfl_xor(ls[r], msk);
            #pragma unroll
            for (int r = 0; r < 4; ++r) l_run[r] = l_run[r] * alpha[r] + ls[r];
            #pragma unroll
            for (int ds = 0; ds < 8; ++ds)
                #pragma unroll
                for (int r = 0; r < 4; ++r) of[ds][r] *= alpha[r];

            // ---- O += P V ----
            f16x8 pa[2];
            #pragma unroll
            for (int kc = 0; kc < 2; ++kc)
                pa[kc] = *(const f16x8*)(PwB + lc * 128 +
                         ((lr * 16 + kc * 64) ^ ((lc & 7) << 4)));
            #pragma unroll
            for (int ds = 0; ds < 8; ++ds) {
                const int d = ds * 16 + lc;
                #pragma unroll
                for (int kc = 0; kc < 2; ++kc) {
                    const f16x8 vb = *(const f16x8*)(VtsB + d * 128 +
                                     ((lr * 16 + kc * 64) ^ ((d & 7) << 4)));
                    of[ds] = __builtin_amdgcn_mfma_f32_16x16x32_f16(
                        pa[kc], vb, of[ds], 0, 0, 0);
                }
            }
        } // KV tiles

        // ---- epilogue: O rows -> f16 Oh (B, L, D) ----
        const int b = bh >> 4, h = bh & (H_ - 1);
        #pragma unroll
        for (int r = 0; r < 4; ++r) {
            const int q = wq0 + lr * 4 + r;
            const float inv = 1.0f / l_run[r];
            f16* orow = Oh + ((size_t)(b * L_ + q)) * D_ + h * HD_;
            #pragma unroll
            for (int ds = 0; ds < 8; ++ds)
                orow[ds * 16 + lc] = (f16)(of[ds][r] * inv);
        }
    } // phases
}

} // anonymous namespace

extern "C" void kernel_launch(void* const* d_in, const int* in_sizes, int n_in,
                              void* d_out, int out_size, void* d_ws, size_t ws_size,
                              hipStream_t stream)
{
    (void)in_sizes; (void)n_in; (void)out_size; (void)ws_size;

    const float* x    = (const float*)d_in[0];
    const float* cosp = (const float*)d_in[1];
    const float* sinp = (const float*)d_in[2];
    const float* Wqkv = (const float*)d_in[3];
    const float* bqkv = (const float*)d_in[4];
    const float* Wd   = (const float*)d_in[5];
    const float* bd   = (const float*)d_in[6];
    float* out = (float*)d_out;

    const size_t SZ = (size_t)B_ * H_ * L_ * HD_;   // 8.39M elems
    f16* Qh = (f16*)d_ws;
    f16* Kh = Qh + SZ;
    f16* Vh = Kh + SZ;
    f16* xh = Vh + SZ;
    f16* Oh = xh;                     // alias: xh dead after QKV GEMMs
    f16* WT = xh + SZ;                // reused per slice + Wd
    // peak ws: 5 * 16.78 MB = 84 MB

    const dim3 gT(64, 64), gG(16, 32);

    cast_x_k<<<8192, 256, 0, stream>>>(x, xh);

    transW_k<1><<<gT, 256, 0, stream>>>(Wqkv, WT);
    hgemm_k<1><<<gG, 256, 0, stream>>>(xh, WT, bqkv, Qh);
    transW_k<2><<<gT, 256, 0, stream>>>(Wqkv, WT);
    hgemm_k<2><<<gG, 256, 0, stream>>>(xh, WT, bqkv, Kh);
    transW_k<3><<<gT, 256, 0, stream>>>(Wqkv, WT);
    hgemm_k<3><<<gG, 256, 0, stream>>>(xh, WT, bqkv, Vh);

    rope_k<<<4096, 256, 0, stream>>>(Qh, Kh, cosp, sinp);

    attn2_k<<<dim3(16, 32), 256, 0, stream>>>(Qh, Kh, Vh, Oh);

    transW_k<0><<<gT, 256, 0, stream>>>(Wd, WT);
    hgemm_k<0><<<gG, 256, 0, stream>>>(Oh, WT, bd, out);
}